// Round 7
// baseline (466.000 us; speedup 1.0000x reference)
//
#include <hip/hip_runtime.h>
#include <hip/hip_bf16.h>
#include <stdint.h>

#define D_MODEL 1024
#define NHEAD   16
#define DK      64
#define BATCH   4
#define SEQ     2048
#define MROWS   (BATCH*SEQ)   // 8192

typedef __hip_bfloat16 bf16;
typedef __attribute__((ext_vector_type(8))) short short8;
typedef __attribute__((ext_vector_type(4))) float f32x4;
typedef __attribute__((ext_vector_type(4))) unsigned int uint4t;

typedef __attribute__((address_space(1))) unsigned int as1_uint;
typedef __attribute__((address_space(3))) unsigned int as3_uint;

#define MFMA32(a,b,c) __builtin_amdgcn_mfma_f32_16x16x32_bf16((a),(b),(c),0,0,0)

static __device__ __forceinline__ void load_lds16(const bf16* g, bf16* l) {
  __builtin_amdgcn_global_load_lds((const as1_uint*)g, (as3_uint*)l, 16, 0, 0);
}

static __device__ __forceinline__ unsigned short bfbits(float x) {
  __hip_bfloat16 h = __float2bfloat16(x);
  return __builtin_bit_cast(unsigned short, h);
}

// RNE pack (used in casts / GEMM epilogues, off the hot path)
static __device__ __forceinline__ unsigned int pack2(float lo, float hi) {
  return (unsigned int)bfbits(lo) | ((unsigned int)bfbits(hi) << 16);
}

// truncation pack: ~1 VALU inst (v_perm). P in [0,1]; bias cancels because
// lsum is computed from the SAME truncated fragments (consistent weights).
static __device__ __forceinline__ unsigned int pack2t(float lo, float hi) {
  return (__builtin_bit_cast(unsigned int, lo) >> 16) |
         (__builtin_bit_cast(unsigned int, hi) & 0xffff0000u);
}

// ---------------------------------------------------------------- cast kernels
__global__ __launch_bounds__(256) void cast_w(const float* __restrict__ i0,
                                              const float* __restrict__ i1,
                                              const float* __restrict__ i2,
                                              const float* __restrict__ i3,
                                              bf16* o0, bf16* o1, bf16* o2, bf16* o3,
                                              float s1) {
  const int z = blockIdx.z;
  const float* in = z == 0 ? i0 : (z == 1 ? i1 : (z == 2 ? i2 : i3));
  bf16* out = z == 0 ? o0 : (z == 1 ? o1 : (z == 2 ? o2 : o3));
  const float s = (z == 1) ? s1 : 1.0f;
  int i = blockIdx.x * 256 + threadIdx.x;
  const float4* p = (const float4*)in;
  float4 a = p[2 * (size_t)i];
  float4 b = p[2 * (size_t)i + 1];
  uint4t u;
  u.x = pack2(a.x * s, a.y * s);
  u.y = pack2(a.z * s, a.w * s);
  u.z = pack2(b.x * s, b.y * s);
  u.w = pack2(b.z * s, b.w * s);
  *(uint4t*)(out + (size_t)i * 8) = u;
}

__global__ __launch_bounds__(256) void cast_x(const float* __restrict__ i0,
                                              const float* __restrict__ i1,
                                              const float* __restrict__ i2,
                                              bf16* o0, bf16* o1, bf16* o2) {
  const int z = blockIdx.z;
  const float* in = z == 0 ? i0 : (z == 1 ? i1 : i2);
  bf16* out = z == 0 ? o0 : (z == 1 ? o1 : o2);
  int i = blockIdx.x * 256 + threadIdx.x;
  const float4* p = (const float4*)in;
  float4 a = p[2 * (size_t)i];
  float4 b = p[2 * (size_t)i + 1];
  uint4t u;
  u.x = pack2(a.x, a.y);
  u.y = pack2(a.z, a.w);
  u.z = pack2(b.x, b.y);
  u.w = pack2(b.z, b.w);
  *(uint4t*)(out + (size_t)i * 8) = u;
}

// ------------------------------------------------------------ shared GEMM loop pieces
// Double-buffered 2-phase (T3-minimum recipe): STAGE(next, other buf) issued
// BEFORE ds_read+MFMA of current buf; single vmcnt(0)+barrier per tile.
// (R6's 3-buf counted-vmcnt pipeline FAILED correctness — reverted to this
// race-screened R3 structure. Do not change sync structure again.)
#define GEMM_STAGE(BUFOFF, KT) do {                                   \
    load_lds16(Ag0 + (KT), As + (BUFOFF) + w * 512);                  \
    load_lds16(Ag1 + (KT), As + (BUFOFF) + 2048 + w * 512);           \
    load_lds16(Bg0 + (KT), Bs + (BUFOFF) + w * 512);                  \
    load_lds16(Bg1 + (KT), Bs + (BUFOFF) + 2048 + w * 512);           \
  } while (0)

#define GEMM_COMPUTE(BUFOFF) do {                                              \
    short8 af[4], bf_[4];                                                      \
    _Pragma("unroll") for (int i = 0; i < 4; ++i) {                            \
      af[i]  = *(const short8*)(As + (BUFOFF) + (wm + i * 16 + lm) * 32 + lq * 8); \
      bf_[i] = *(const short8*)(Bs + (BUFOFF) + (wn + i * 16 + lm) * 32 + lq * 8); \
    }                                                                          \
    _Pragma("unroll") for (int i = 0; i < 4; ++i)                              \
      _Pragma("unroll") for (int j = 0; j < 4; ++j)                            \
        acc[i][j] = MFMA32(af[i], bf_[j], acc[i][j]);                          \
  } while (0)

#define VMCNT0_BAR() do {                                   \
    asm volatile("s_waitcnt vmcnt(0)" ::: "memory");        \
    __syncthreads();                                        \
  } while (0)

// ---------------------------------------------------------------- projection GEMMs
// Grid is (M-tiles, N-tiles, z): linear id = mTile + 64*nTile, so id%8 (XCD)
// = mTile%8 -> each XCD keeps an ~2MB A row-chunk L2-resident across all 8
// N-tiles.
__global__ __launch_bounds__(256) void gemm_proj(const bf16* __restrict__ A0,
                                                 const bf16* __restrict__ A1,
                                                 const bf16* __restrict__ A2,
                                                 const bf16* __restrict__ B0,
                                                 const bf16* __restrict__ B1,
                                                 const bf16* __restrict__ B2,
                                                 bf16* C0, bf16* C1, bf16* C2) {
  const int z = blockIdx.z;
  const bf16* A = z == 0 ? A0 : (z == 1 ? A1 : A2);
  const bf16* B = z == 0 ? B0 : (z == 1 ? B1 : B2);
  bf16* C = z == 0 ? C0 : (z == 1 ? C1 : C2);
  const int M = MROWS, N = D_MODEL, K = D_MODEL;

  __shared__ bf16 As[2 * 128 * 32];
  __shared__ bf16 Bs[2 * 128 * 32];
  const int t = threadIdx.x;
  const int w = t >> 6;
  const int lane = t & 63;
  const int lm = lane & 15;
  const int lq = lane >> 4;
  const int wm = (w >> 1) * 64;
  const int wn = (w & 1) * 64;
  const long rowA = (long)blockIdx.x * 128;   // M-tile (grid transposed)
  const long rowB = (long)blockIdx.y * 128;   // N-tile

  const int srow = t >> 2;
  const int scol = (t & 3) * 8;
  const bf16* Ag0 = A + (rowA + srow) * K + scol;
  const bf16* Ag1 = A + (rowA + 64 + srow) * K + scol;
  const bf16* Bg0 = B + (rowB + srow) * K + scol;
  const bf16* Bg1 = B + (rowB + 64 + srow) * K + scol;

  const f32x4 fzero = {0.f, 0.f, 0.f, 0.f};
  f32x4 acc[4][4];
#pragma unroll
  for (int i = 0; i < 4; ++i)
#pragma unroll
    for (int j = 0; j < 4; ++j) acc[i][j] = fzero;

  GEMM_STAGE(0, 0);
  VMCNT0_BAR();
  for (int kt = 0; kt < K; kt += 64) {
    if (kt + 32 < K) GEMM_STAGE(4096, kt + 32);
    GEMM_COMPUTE(0);
    VMCNT0_BAR();
    if (kt + 64 < K) GEMM_STAGE(0, kt + 64);
    GEMM_COMPUTE(4096);
    VMCNT0_BAR();
  }

  if (z < 2) {
#pragma unroll
    for (int i = 0; i < 4; ++i) {
      long r0 = rowA + wm + i * 16 + lq * 4;
#pragma unroll
      for (int j = 0; j < 4; ++j) {
        long c = rowB + wn + j * 16 + lm;
#pragma unroll
        for (int r = 0; r < 4; ++r)
          C[(r0 + r) * N + c] = __float2bfloat16(acc[i][j][r]);
      }
    }
  } else {
    // Vt[d][s'] with s' kv-interleaved: s=tile*64+half*16+m -> s'=tile*64+m*2+half
#pragma unroll
    for (int j = 0; j < 4; ++j) {
      long c = rowB + wn + j * 16 + lm;  // d
#pragma unroll
      for (int i = 0; i < 4; ++i) {
        long r0 = rowA + wm + i * 16 + lq * 4;  // s base, 4 consecutive
        long sp = (r0 & ~63L) | (((r0 >> 5) & 1) * 32) | ((r0 & 15) * 2) | ((r0 >> 4) & 1);
#pragma unroll
        for (int r = 0; r < 4; ++r)
          C[c * M + sp + r * 2] = __float2bfloat16(acc[i][j][r]);
      }
    }
  }
}

// ---------------------------------------------------------------- output GEMM (+bias, fp32 out)
__global__ __launch_bounds__(256) void gemm_out(const bf16* __restrict__ A,
                                                const bf16* __restrict__ B,
                                                float* __restrict__ C,
                                                const float* __restrict__ bias) {
  const int M = MROWS, N = D_MODEL, K = D_MODEL;
  __shared__ bf16 As[2 * 128 * 32];
  __shared__ bf16 Bs[2 * 128 * 32];
  const int t = threadIdx.x;
  const int w = t >> 6;
  const int lane = t & 63;
  const int lm = lane & 15;
  const int lq = lane >> 4;
  const int wm = (w >> 1) * 64;
  const int wn = (w & 1) * 64;
  const long rowA = (long)blockIdx.x * 128;   // M-tile (grid transposed)
  const long rowB = (long)blockIdx.y * 128;   // N-tile

  const int srow = t >> 2;
  const int scol = (t & 3) * 8;
  const bf16* Ag0 = A + (rowA + srow) * K + scol;
  const bf16* Ag1 = A + (rowA + 64 + srow) * K + scol;
  const bf16* Bg0 = B + (rowB + srow) * K + scol;
  const bf16* Bg1 = B + (rowB + 64 + srow) * K + scol;

  const f32x4 fzero = {0.f, 0.f, 0.f, 0.f};
  f32x4 acc[4][4];
#pragma unroll
  for (int i = 0; i < 4; ++i)
#pragma unroll
    for (int j = 0; j < 4; ++j) acc[i][j] = fzero;

  GEMM_STAGE(0, 0);
  VMCNT0_BAR();
  for (int kt = 0; kt < K; kt += 64) {
    if (kt + 32 < K) GEMM_STAGE(4096, kt + 32);
    GEMM_COMPUTE(0);
    VMCNT0_BAR();
    if (kt + 64 < K) GEMM_STAGE(0, kt + 64);
    GEMM_COMPUTE(4096);
    VMCNT0_BAR();
  }

#pragma unroll
  for (int j = 0; j < 4; ++j) {
    long c = rowB + wn + j * 16 + lm;
    float bz = bias[c];
#pragma unroll
    for (int i = 0; i < 4; ++i) {
      long r0 = rowA + wm + i * 16 + lq * 4;
#pragma unroll
      for (int r = 0; r < 4; ++r)
        C[(r0 + r) * N + c] = acc[i][j][r] + bz;
    }
  }
}

// ---------------------------------------------------------------- flash attention v5 + T5 setprio
// Exact R3 structure (known-good 73.6 µs) with ONE addition: s_setprio(1)
// around the MFMA clusters (m191: +4-7% on attn, pure scheduler hint, no
// correctness surface). attn has 4 waves/SIMD at different phases -> the
// role-diversity regime where setprio pays.
__global__ __launch_bounds__(256, 4) void attn_kernel(const bf16* __restrict__ Qb,
                                                      const bf16* __restrict__ Kb,
                                                      const bf16* __restrict__ Vt,
                                                      bf16* __restrict__ ctx) {
  __shared__ bf16 Ks[64 * 64];
  __shared__ bf16 Vs[64 * 64];
  const int t = threadIdx.x;
  const int w = t >> 6;
  const int lane = t & 63;
  const int lm = lane & 15;
  const int lq = lane >> 4;
  const int bh = blockIdx.x;
  const int b = bh >> 4;
  const int h = bh & 15;
  const int q0 = blockIdx.y * 128 + w * 32;

  const bf16* Qh = Qb + (long)b * SEQ * D_MODEL + h * DK;
  const bf16* Kh = Kb + (long)b * SEQ * D_MODEL + h * DK;
  const bf16* Vh = Vt + (long)h * DK * MROWS + (long)b * SEQ;

  const int sr = lane >> 3;
  const int sc = ((lane & 7) ^ sr) * 8;      // XOR-swizzled staging column
  const bf16* kg0 = Kh + (long)(w * 8 + sr) * D_MODEL + sc;
  const bf16* kg1 = Kh + (long)(32 + w * 8 + sr) * D_MODEL + sc;
  const bf16* vg0 = Vh + (long)(w * 8 + sr) * MROWS + sc;
  const bf16* vg1 = Vh + (long)(32 + w * 8 + sr) * MROWS + sc;
  bf16* lk0 = Ks + w * 512;
  bf16* lk1 = Ks + 2048 + w * 512;
  bf16* lv0 = Vs + w * 512;
  bf16* lv1 = Vs + 2048 + w * 512;

  short8 qf[2][2];
#pragma unroll
  for (int qt = 0; qt < 2; ++qt)
#pragma unroll
    for (int ks = 0; ks < 2; ++ks)
      qf[qt][ks] = *(const short8*)(Qh + (long)(q0 + qt * 16 + lm) * D_MODEL + ks * 32 + lq * 8);

  uint4t uo;
  uo.x = 0x3F803F80u; uo.y = 0x3F803F80u; uo.z = 0x3F803F80u; uo.w = 0x3F803F80u;
  const short8 ones8 = __builtin_bit_cast(short8, uo);

  const f32x4 fzero = {0.f, 0.f, 0.f, 0.f};
  f32x4 O[2][4];
  f32x4 lsum[2];
#pragma unroll
  for (int qt = 0; qt < 2; ++qt) {
    lsum[qt] = fzero;
#pragma unroll
    for (int dt = 0; dt < 4; ++dt) O[qt][dt] = fzero;
  }

  const int xs = lm & 7;

  for (int kv = 0; kv < SEQ; kv += 64) {
    load_lds16(kg0, lk0);
    load_lds16(kg1, lk1);
    load_lds16(vg0, lv0);
    load_lds16(vg1, lv1);
    kg0 += 64 * D_MODEL; kg1 += 64 * D_MODEL;
    vg0 += 64; vg1 += 64;
    asm volatile("s_waitcnt vmcnt(0)" ::: "memory");
    __syncthreads();

    short8 kf[4][2];
#pragma unroll
    for (int c = 0; c < 4; ++c)
#pragma unroll
      for (int ks = 0; ks < 2; ++ks)
        kf[c][ks] = *(const short8*)(Ks + (c * 16 + lm) * 64 + (((ks * 4 + lq) ^ xs) * 8));
    short8 vf[4][2];
#pragma unroll
    for (int dt = 0; dt < 4; ++dt)
#pragma unroll
      for (int tt = 0; tt < 2; ++tt)
        vf[dt][tt] = *(const short8*)(Vs + (dt * 16 + lm) * 64 + (((tt * 4 + lq) ^ xs) * 8));

#pragma unroll
    for (int qt = 0; qt < 2; ++qt) {
      f32x4 st[4];
      // first K-slice consumes the persistent zero C (no per-qt re-zeroing)
      __builtin_amdgcn_s_setprio(1);
#pragma unroll
      for (int c = 0; c < 4; ++c)
        st[c] = MFMA32(kf[c][0], qf[qt][0], fzero);
#pragma unroll
      for (int c = 0; c < 4; ++c)
        st[c] = MFMA32(kf[c][1], qf[qt][1], st[c]);  // St[kv][q], pre-scaled
      __builtin_amdgcn_s_setprio(0);

      float pe[4][4];
#pragma unroll
      for (int c = 0; c < 4; ++c)
#pragma unroll
        for (int r = 0; r < 4; ++r)
          pe[c][r] = __builtin_amdgcn_exp2f(st[c][r]);

      short8 pf8[2];
#pragma unroll
      for (int tt = 0; tt < 2; ++tt) {
        uint4t u;
        u.x = pack2t(pe[2 * tt][0], pe[2 * tt + 1][0]);
        u.y = pack2t(pe[2 * tt][1], pe[2 * tt + 1][1]);
        u.z = pack2t(pe[2 * tt][2], pe[2 * tt + 1][2]);
        u.w = pack2t(pe[2 * tt][3], pe[2 * tt + 1][3]);
        pf8[tt] = __builtin_bit_cast(short8, u);
      }

      __builtin_amdgcn_s_setprio(1);
#pragma unroll
      for (int tt = 0; tt < 2; ++tt) {
        lsum[qt] = MFMA32(pf8[tt], ones8, lsum[qt]);
#pragma unroll
        for (int dt = 0; dt < 4; ++dt)
          O[qt][dt] = MFMA32(pf8[tt], vf[dt][tt], O[qt][dt]);
      }
      __builtin_amdgcn_s_setprio(0);
    }
    __syncthreads();
  }

#pragma unroll
  for (int qt = 0; qt < 2; ++qt) {
    f32x4 linv;
#pragma unroll
    for (int r = 0; r < 4; ++r) linv[r] = 1.f / lsum[qt][r];
#pragma unroll
    for (int r = 0; r < 4; ++r) {
      long qrow = (long)b * SEQ + q0 + qt * 16 + lq * 4 + r;
#pragma unroll
      for (int dt = 0; dt < 4; ++dt)
        ctx[qrow * D_MODEL + h * DK + dt * 16 + lm] =
            __float2bfloat16(O[qt][dt][r] * linv[r]);
    }
  }
}

// ---------------------------------------------------------------- launch
extern "C" void kernel_launch(void* const* d_in, const int* in_sizes, int n_in,
                              void* d_out, int out_size, void* d_ws, size_t ws_size,
                              hipStream_t stream) {
  const float* q  = (const float*)d_in[0];
  const float* k  = (const float*)d_in[1];
  const float* v  = (const float*)d_in[2];
  const float* wq = (const float*)d_in[3];
  const float* wk = (const float*)d_in[4];
  const float* wv = (const float*)d_in[5];
  const float* wo = (const float*)d_in[6];
  const float* bo = (const float*)d_in[7];

  char* ws = (char*)d_ws;
  const size_t SZW = (size_t)D_MODEL * D_MODEL * sizeof(bf16);  // 2 MB
  const size_t SZX = (size_t)MROWS * D_MODEL * sizeof(bf16);    // 16.78 MB
  bf16* Wq = (bf16*)(ws + 0 * SZW);
  bf16* Wk = (bf16*)(ws + 1 * SZW);
  bf16* Wv = (bf16*)(ws + 2 * SZW);
  bf16* Wo = (bf16*)(ws + 3 * SZW);
  bf16* Xq = (bf16*)(ws + 4 * SZW + 0 * SZX);
  bf16* Xk = (bf16*)(ws + 4 * SZW + 1 * SZX);
  bf16* Xv = (bf16*)(ws + 4 * SZW + 2 * SZX);
  bf16* Qb = (bf16*)(ws + 4 * SZW + 3 * SZX);
  bf16* Kb = (bf16*)(ws + 4 * SZW + 4 * SZX);
  bf16* Vt = Xq;  // Xq dead after Q projection
  bf16* Cx = Xk;  // Xk dead after K projection

  const float SCL = 0.18033688011112042f;  // (1/sqrt(64)) * log2(e), folded into Wk
  const int NW8 = D_MODEL * D_MODEL / 8;
  const int NX8 = MROWS * D_MODEL / 8;

  cast_w<<<dim3(NW8 / 256, 1, 4), 256, 0, stream>>>(wq, wk, wv, wo, Wq, Wk, Wv, Wo, SCL);
  cast_x<<<dim3(NX8 / 256, 1, 3), 256, 0, stream>>>(q, k, v, Xq, Xk, Xv);

  // grid transposed: (M-tiles, N-tiles, z) for XCD L2 reuse of A row-panels
  gemm_proj<<<dim3(MROWS / 128, D_MODEL / 128, 3), 256, 0, stream>>>(
      Xq, Xk, Xv, Wq, Wk, Wv, Qb, Kb, Vt);

  attn_kernel<<<dim3(BATCH * NHEAD, SEQ / 128), 256, 0, stream>>>(Qb, Kb, Vt, Cx);

  gemm_out<<<dim3(MROWS / 128, D_MODEL / 128), 256, 0, stream>>>(Cx, Wo, (float*)d_out, bo);
}

// Round 8
// 327.127 us; speedup vs baseline: 1.4245x; 1.4245x over previous
//
#include <hip/hip_runtime.h>
#include <hip/hip_bf16.h>
#include <stdint.h>

#define D_MODEL 1024
#define NHEAD   16
#define DK      64
#define BATCH   4
#define SEQ     2048
#define MROWS   (BATCH*SEQ)   // 8192

typedef __hip_bfloat16 bf16;
typedef __attribute__((ext_vector_type(8))) short short8;
typedef __attribute__((ext_vector_type(4))) float f32x4;
typedef __attribute__((ext_vector_type(4))) unsigned int uint4t;

typedef __attribute__((address_space(1))) unsigned int as1_uint;
typedef __attribute__((address_space(3))) unsigned int as3_uint;

#define MFMA32(a,b,c) __builtin_amdgcn_mfma_f32_16x16x32_bf16((a),(b),(c),0,0,0)

static __device__ __forceinline__ void load_lds16(const bf16* g, bf16* l) {
  __builtin_amdgcn_global_load_lds((const as1_uint*)g, (as3_uint*)l, 16, 0, 0);
}

static __device__ __forceinline__ unsigned short bfbits(float x) {
  __hip_bfloat16 h = __float2bfloat16(x);
  return __builtin_bit_cast(unsigned short, h);
}

// RNE pack (used in casts / GEMM epilogues, off the hot path)
static __device__ __forceinline__ unsigned int pack2(float lo, float hi) {
  return (unsigned int)bfbits(lo) | ((unsigned int)bfbits(hi) << 16);
}

// truncation pack: ~1 VALU inst (v_perm). P in [0,1]; bias cancels because
// lsum is computed from the SAME truncated fragments (consistent weights).
static __device__ __forceinline__ unsigned int pack2t(float lo, float hi) {
  return (__builtin_bit_cast(unsigned int, lo) >> 16) |
         (__builtin_bit_cast(unsigned int, hi) & 0xffff0000u);
}

// ---------------------------------------------------------------- cast kernels
__global__ __launch_bounds__(256) void cast_w(const float* __restrict__ i0,
                                              const float* __restrict__ i1,
                                              const float* __restrict__ i2,
                                              const float* __restrict__ i3,
                                              bf16* o0, bf16* o1, bf16* o2, bf16* o3,
                                              float s1) {
  const int z = blockIdx.z;
  const float* in = z == 0 ? i0 : (z == 1 ? i1 : (z == 2 ? i2 : i3));
  bf16* out = z == 0 ? o0 : (z == 1 ? o1 : (z == 2 ? o2 : o3));
  const float s = (z == 1) ? s1 : 1.0f;
  int i = blockIdx.x * 256 + threadIdx.x;
  const float4* p = (const float4*)in;
  float4 a = p[2 * (size_t)i];
  float4 b = p[2 * (size_t)i + 1];
  uint4t u;
  u.x = pack2(a.x * s, a.y * s);
  u.y = pack2(a.z * s, a.w * s);
  u.z = pack2(b.x * s, b.y * s);
  u.w = pack2(b.z * s, b.w * s);
  *(uint4t*)(out + (size_t)i * 8) = u;
}

__global__ __launch_bounds__(256) void cast_x(const float* __restrict__ i0,
                                              const float* __restrict__ i1,
                                              const float* __restrict__ i2,
                                              bf16* o0, bf16* o1, bf16* o2) {
  const int z = blockIdx.z;
  const float* in = z == 0 ? i0 : (z == 1 ? i1 : i2);
  bf16* out = z == 0 ? o0 : (z == 1 ? o1 : o2);
  int i = blockIdx.x * 256 + threadIdx.x;
  const float4* p = (const float4*)in;
  float4 a = p[2 * (size_t)i];
  float4 b = p[2 * (size_t)i + 1];
  uint4t u;
  u.x = pack2(a.x, a.y);
  u.y = pack2(a.z, a.w);
  u.z = pack2(b.x, b.y);
  u.w = pack2(b.z, b.w);
  *(uint4t*)(out + (size_t)i * 8) = u;
}

// ------------------------------------------------------------ shared GEMM loop pieces
// Double-buffered 2-phase (T3-minimum recipe): STAGE(next, other buf) issued
// BEFORE ds_read+MFMA of current buf; single vmcnt(0)+barrier per tile.
// (R6's 3-buf counted-vmcnt pipeline FAILED correctness — this is the
// race-screened R3 structure. Do not change sync structure.)
#define GEMM_STAGE(BUFOFF, KT) do {                                   \
    load_lds16(Ag0 + (KT), As + (BUFOFF) + w * 512);                  \
    load_lds16(Ag1 + (KT), As + (BUFOFF) + 2048 + w * 512);           \
    load_lds16(Bg0 + (KT), Bs + (BUFOFF) + w * 512);                  \
    load_lds16(Bg1 + (KT), Bs + (BUFOFF) + 2048 + w * 512);           \
  } while (0)

#define GEMM_COMPUTE(BUFOFF) do {                                              \
    short8 af[4], bf_[4];                                                      \
    _Pragma("unroll") for (int i = 0; i < 4; ++i) {                            \
      af[i]  = *(const short8*)(As + (BUFOFF) + (wm + i * 16 + lm) * 32 + lq * 8); \
      bf_[i] = *(const short8*)(Bs + (BUFOFF) + (wn + i * 16 + lm) * 32 + lq * 8); \
    }                                                                          \
    _Pragma("unroll") for (int i = 0; i < 4; ++i)                              \
      _Pragma("unroll") for (int j = 0; j < 4; ++j)                            \
        acc[i][j] = MFMA32(af[i], bf_[j], acc[i][j]);                          \
  } while (0)

#define VMCNT0_BAR() do {                                   \
    asm volatile("s_waitcnt vmcnt(0)" ::: "memory");        \
    __syncthreads();                                        \
  } while (0)

// ---------------------------------------------------------------- projection GEMMs
// Grid is (M-tiles, N-tiles, z): linear id = mTile + 64*nTile, so id%8 (XCD)
// = mTile%8 -> each XCD keeps an ~2MB A row-chunk L2-resident across all 8
// N-tiles.
__global__ __launch_bounds__(256) void gemm_proj(const bf16* __restrict__ A0,
                                                 const bf16* __restrict__ A1,
                                                 const bf16* __restrict__ A2,
                                                 const bf16* __restrict__ B0,
                                                 const bf16* __restrict__ B1,
                                                 const bf16* __restrict__ B2,
                                                 bf16* C0, bf16* C1, bf16* C2) {
  const int z = blockIdx.z;
  const bf16* A = z == 0 ? A0 : (z == 1 ? A1 : A2);
  const bf16* B = z == 0 ? B0 : (z == 1 ? B1 : B2);
  bf16* C = z == 0 ? C0 : (z == 1 ? C1 : C2);
  const int M = MROWS, N = D_MODEL, K = D_MODEL;

  __shared__ bf16 As[2 * 128 * 32];
  __shared__ bf16 Bs[2 * 128 * 32];
  const int t = threadIdx.x;
  const int w = t >> 6;
  const int lane = t & 63;
  const int lm = lane & 15;
  const int lq = lane >> 4;
  const int wm = (w >> 1) * 64;
  const int wn = (w & 1) * 64;
  const long rowA = (long)blockIdx.x * 128;   // M-tile (grid transposed)
  const long rowB = (long)blockIdx.y * 128;   // N-tile

  const int srow = t >> 2;
  const int scol = (t & 3) * 8;
  const bf16* Ag0 = A + (rowA + srow) * K + scol;
  const bf16* Ag1 = A + (rowA + 64 + srow) * K + scol;
  const bf16* Bg0 = B + (rowB + srow) * K + scol;
  const bf16* Bg1 = B + (rowB + 64 + srow) * K + scol;

  const f32x4 fzero = {0.f, 0.f, 0.f, 0.f};
  f32x4 acc[4][4];
#pragma unroll
  for (int i = 0; i < 4; ++i)
#pragma unroll
    for (int j = 0; j < 4; ++j) acc[i][j] = fzero;

  GEMM_STAGE(0, 0);
  VMCNT0_BAR();
  for (int kt = 0; kt < K; kt += 64) {
    if (kt + 32 < K) GEMM_STAGE(4096, kt + 32);
    GEMM_COMPUTE(0);
    VMCNT0_BAR();
    if (kt + 64 < K) GEMM_STAGE(0, kt + 64);
    GEMM_COMPUTE(4096);
    VMCNT0_BAR();
  }

  if (z < 2) {
#pragma unroll
    for (int i = 0; i < 4; ++i) {
      long r0 = rowA + wm + i * 16 + lq * 4;
#pragma unroll
      for (int j = 0; j < 4; ++j) {
        long c = rowB + wn + j * 16 + lm;
#pragma unroll
        for (int r = 0; r < 4; ++r)
          C[(r0 + r) * N + c] = __float2bfloat16(acc[i][j][r]);
      }
    }
  } else {
    // Vt[d][s'] with s' kv-interleaved: s=tile*64+half*16+m -> s'=tile*64+m*2+half
#pragma unroll
    for (int j = 0; j < 4; ++j) {
      long c = rowB + wn + j * 16 + lm;  // d
#pragma unroll
      for (int i = 0; i < 4; ++i) {
        long r0 = rowA + wm + i * 16 + lq * 4;  // s base, 4 consecutive
        long sp = (r0 & ~63L) | (((r0 >> 5) & 1) * 32) | ((r0 & 15) * 2) | ((r0 >> 4) & 1);
#pragma unroll
        for (int r = 0; r < 4; ++r)
          C[c * M + sp + r * 2] = __float2bfloat16(acc[i][j][r]);
      }
    }
  }
}

// ---------------------------------------------------------------- output GEMM (+bias, fp32 out)
__global__ __launch_bounds__(256) void gemm_out(const bf16* __restrict__ A,
                                                const bf16* __restrict__ B,
                                                float* __restrict__ C,
                                                const float* __restrict__ bias) {
  const int M = MROWS, N = D_MODEL, K = D_MODEL;
  __shared__ bf16 As[2 * 128 * 32];
  __shared__ bf16 Bs[2 * 128 * 32];
  const int t = threadIdx.x;
  const int w = t >> 6;
  const int lane = t & 63;
  const int lm = lane & 15;
  const int lq = lane >> 4;
  const int wm = (w >> 1) * 64;
  const int wn = (w & 1) * 64;
  const long rowA = (long)blockIdx.x * 128;   // M-tile (grid transposed)
  const long rowB = (long)blockIdx.y * 128;   // N-tile

  const int srow = t >> 2;
  const int scol = (t & 3) * 8;
  const bf16* Ag0 = A + (rowA + srow) * K + scol;
  const bf16* Ag1 = A + (rowA + 64 + srow) * K + scol;
  const bf16* Bg0 = B + (rowB + srow) * K + scol;
  const bf16* Bg1 = B + (rowB + 64 + srow) * K + scol;

  const f32x4 fzero = {0.f, 0.f, 0.f, 0.f};
  f32x4 acc[4][4];
#pragma unroll
  for (int i = 0; i < 4; ++i)
#pragma unroll
    for (int j = 0; j < 4; ++j) acc[i][j] = fzero;

  GEMM_STAGE(0, 0);
  VMCNT0_BAR();
  for (int kt = 0; kt < K; kt += 64) {
    if (kt + 32 < K) GEMM_STAGE(4096, kt + 32);
    GEMM_COMPUTE(0);
    VMCNT0_BAR();
    if (kt + 64 < K) GEMM_STAGE(0, kt + 64);
    GEMM_COMPUTE(4096);
    VMCNT0_BAR();
  }

#pragma unroll
  for (int j = 0; j < 4; ++j) {
    long c = rowB + wn + j * 16 + lm;
    float bz = bias[c];
#pragma unroll
    for (int i = 0; i < 4; ++i) {
      long r0 = rowA + wm + i * 16 + lq * 4;
#pragma unroll
      for (int r = 0; r < 4; ++r)
        C[(r0 + r) * N + c] = acc[i][j][r] + bz;
    }
  }
}

// ---------------------------------------------------------------- flash attention v5 (R3-exact; setprio removed as R7 control)
__global__ __launch_bounds__(256, 4) void attn_kernel(const bf16* __restrict__ Qb,
                                                      const bf16* __restrict__ Kb,
                                                      const bf16* __restrict__ Vt,
                                                      bf16* __restrict__ ctx) {
  __shared__ bf16 Ks[64 * 64];
  __shared__ bf16 Vs[64 * 64];
  const int t = threadIdx.x;
  const int w = t >> 6;
  const int lane = t & 63;
  const int lm = lane & 15;
  const int lq = lane >> 4;
  const int bh = blockIdx.x;
  const int b = bh >> 4;
  const int h = bh & 15;
  const int q0 = blockIdx.y * 128 + w * 32;

  const bf16* Qh = Qb + (long)b * SEQ * D_MODEL + h * DK;
  const bf16* Kh = Kb + (long)b * SEQ * D_MODEL + h * DK;
  const bf16* Vh = Vt + (long)h * DK * MROWS + (long)b * SEQ;

  const int sr = lane >> 3;
  const int sc = ((lane & 7) ^ sr) * 8;      // XOR-swizzled staging column
  const bf16* kg0 = Kh + (long)(w * 8 + sr) * D_MODEL + sc;
  const bf16* kg1 = Kh + (long)(32 + w * 8 + sr) * D_MODEL + sc;
  const bf16* vg0 = Vh + (long)(w * 8 + sr) * MROWS + sc;
  const bf16* vg1 = Vh + (long)(32 + w * 8 + sr) * MROWS + sc;
  bf16* lk0 = Ks + w * 512;
  bf16* lk1 = Ks + 2048 + w * 512;
  bf16* lv0 = Vs + w * 512;
  bf16* lv1 = Vs + 2048 + w * 512;

  short8 qf[2][2];
#pragma unroll
  for (int qt = 0; qt < 2; ++qt)
#pragma unroll
    for (int ks = 0; ks < 2; ++ks)
      qf[qt][ks] = *(const short8*)(Qh + (long)(q0 + qt * 16 + lm) * D_MODEL + ks * 32 + lq * 8);

  uint4t uo;
  uo.x = 0x3F803F80u; uo.y = 0x3F803F80u; uo.z = 0x3F803F80u; uo.w = 0x3F803F80u;
  const short8 ones8 = __builtin_bit_cast(short8, uo);

  const f32x4 fzero = {0.f, 0.f, 0.f, 0.f};
  f32x4 O[2][4];
  f32x4 lsum[2];
#pragma unroll
  for (int qt = 0; qt < 2; ++qt) {
    lsum[qt] = fzero;
#pragma unroll
    for (int dt = 0; dt < 4; ++dt) O[qt][dt] = fzero;
  }

  const int xs = lm & 7;

  for (int kv = 0; kv < SEQ; kv += 64) {
    load_lds16(kg0, lk0);
    load_lds16(kg1, lk1);
    load_lds16(vg0, lv0);
    load_lds16(vg1, lv1);
    kg0 += 64 * D_MODEL; kg1 += 64 * D_MODEL;
    vg0 += 64; vg1 += 64;
    asm volatile("s_waitcnt vmcnt(0)" ::: "memory");
    __syncthreads();

    short8 kf[4][2];
#pragma unroll
    for (int c = 0; c < 4; ++c)
#pragma unroll
      for (int ks = 0; ks < 2; ++ks)
        kf[c][ks] = *(const short8*)(Ks + (c * 16 + lm) * 64 + (((ks * 4 + lq) ^ xs) * 8));
    short8 vf[4][2];
#pragma unroll
    for (int dt = 0; dt < 4; ++dt)
#pragma unroll
      for (int tt = 0; tt < 2; ++tt)
        vf[dt][tt] = *(const short8*)(Vs + (dt * 16 + lm) * 64 + (((tt * 4 + lq) ^ xs) * 8));

#pragma unroll
    for (int qt = 0; qt < 2; ++qt) {
      f32x4 st[4];
      // first K-slice consumes the persistent zero C (no per-qt re-zeroing)
#pragma unroll
      for (int c = 0; c < 4; ++c)
        st[c] = MFMA32(kf[c][0], qf[qt][0], fzero);
#pragma unroll
      for (int c = 0; c < 4; ++c)
        st[c] = MFMA32(kf[c][1], qf[qt][1], st[c]);  // St[kv][q], pre-scaled

      float pe[4][4];
#pragma unroll
      for (int c = 0; c < 4; ++c)
#pragma unroll
        for (int r = 0; r < 4; ++r)
          pe[c][r] = __builtin_amdgcn_exp2f(st[c][r]);

      short8 pf8[2];
#pragma unroll
      for (int tt = 0; tt < 2; ++tt) {
        uint4t u;
        u.x = pack2t(pe[2 * tt][0], pe[2 * tt + 1][0]);
        u.y = pack2t(pe[2 * tt][1], pe[2 * tt + 1][1]);
        u.z = pack2t(pe[2 * tt][2], pe[2 * tt + 1][2]);
        u.w = pack2t(pe[2 * tt][3], pe[2 * tt + 1][3]);
        pf8[tt] = __builtin_bit_cast(short8, u);
      }

#pragma unroll
      for (int tt = 0; tt < 2; ++tt) {
        lsum[qt] = MFMA32(pf8[tt], ones8, lsum[qt]);
#pragma unroll
        for (int dt = 0; dt < 4; ++dt)
          O[qt][dt] = MFMA32(pf8[tt], vf[dt][tt], O[qt][dt]);
      }
    }
    __syncthreads();
  }

#pragma unroll
  for (int qt = 0; qt < 2; ++qt) {
    f32x4 linv;
#pragma unroll
    for (int r = 0; r < 4; ++r) linv[r] = 1.f / lsum[qt][r];
#pragma unroll
    for (int r = 0; r < 4; ++r) {
      long qrow = (long)b * SEQ + q0 + qt * 16 + lq * 4 + r;
#pragma unroll
      for (int dt = 0; dt < 4; ++dt)
        ctx[qrow * D_MODEL + h * DK + dt * 16 + lm] =
            __float2bfloat16(O[qt][dt][r] * linv[r]);
    }
  }
}

// ---------------------------------------------------------------- launch
extern "C" void kernel_launch(void* const* d_in, const int* in_sizes, int n_in,
                              void* d_out, int out_size, void* d_ws, size_t ws_size,
                              hipStream_t stream) {
  const float* q  = (const float*)d_in[0];
  const float* k  = (const float*)d_in[1];
  const float* v  = (const float*)d_in[2];
  const float* wq = (const float*)d_in[3];
  const float* wk = (const float*)d_in[4];
  const float* wv = (const float*)d_in[5];
  const float* wo = (const float*)d_in[6];
  const float* bo = (const float*)d_in[7];

  char* ws = (char*)d_ws;
  const size_t SZW = (size_t)D_MODEL * D_MODEL * sizeof(bf16);  // 2 MB
  const size_t SZX = (size_t)MROWS * D_MODEL * sizeof(bf16);    // 16.78 MB
  bf16* Wq = (bf16*)(ws + 0 * SZW);
  bf16* Wk = (bf16*)(ws + 1 * SZW);
  bf16* Wv = (bf16*)(ws + 2 * SZW);
  bf16* Wo = (bf16*)(ws + 3 * SZW);
  bf16* Xq = (bf16*)(ws + 4 * SZW + 0 * SZX);
  bf16* Xk = (bf16*)(ws + 4 * SZW + 1 * SZX);
  bf16* Xv = (bf16*)(ws + 4 * SZW + 2 * SZX);
  bf16* Qb = (bf16*)(ws + 4 * SZW + 3 * SZX);
  bf16* Kb = (bf16*)(ws + 4 * SZW + 4 * SZX);
  bf16* Vt = Xq;  // Xq dead after Q projection
  bf16* Cx = Xk;  // Xk dead after K projection

  const float SCL = 0.18033688011112042f;  // (1/sqrt(64)) * log2(e), folded into Wk
  const int NW8 = D_MODEL * D_MODEL / 8;
  const int NX8 = MROWS * D_MODEL / 8;

  cast_w<<<dim3(NW8 / 256, 1, 4), 256, 0, stream>>>(wq, wk, wv, wo, Wq, Wk, Wv, Wo, SCL);
  cast_x<<<dim3(NX8 / 256, 1, 3), 256, 0, stream>>>(q, k, v, Xq, Xk, Xv);

  // grid transposed: (M-tiles, N-tiles, z) for XCD L2 reuse of A row-panels
  gemm_proj<<<dim3(MROWS / 128, D_MODEL / 128, 3), 256, 0, stream>>>(
      Xq, Xk, Xv, Wq, Wk, Wv, Qb, Kb, Vt);

  attn_kernel<<<dim3(BATCH * NHEAD, SEQ / 128), 256, 0, stream>>>(Qb, Kb, Vt, Cx);

  gemm_out<<<dim3(MROWS / 128, D_MODEL / 128), 256, 0, stream>>>(Cx, Wo, (float*)d_out, bo);
}

// Round 9
// 320.624 us; speedup vs baseline: 1.4534x; 1.0203x over previous
//
#include <hip/hip_runtime.h>
#include <hip/hip_bf16.h>
#include <stdint.h>

#define D_MODEL 1024
#define NHEAD   16
#define DK      64
#define BATCH   4
#define SEQ     2048
#define MROWS   (BATCH*SEQ)   // 8192

typedef __hip_bfloat16 bf16;
typedef __attribute__((ext_vector_type(8))) short short8;
typedef __attribute__((ext_vector_type(4))) float f32x4;
typedef __attribute__((ext_vector_type(4))) unsigned int uint4t;

typedef __attribute__((address_space(1))) unsigned int as1_uint;
typedef __attribute__((address_space(3))) unsigned int as3_uint;

#define MFMA32(a,b,c) __builtin_amdgcn_mfma_f32_16x16x32_bf16((a),(b),(c),0,0,0)

static __device__ __forceinline__ void load_lds16(const bf16* g, bf16* l) {
  __builtin_amdgcn_global_load_lds((const as1_uint*)g, (as3_uint*)l, 16, 0, 0);
}

static __device__ __forceinline__ unsigned short bfbits(float x) {
  __hip_bfloat16 h = __float2bfloat16(x);
  return __builtin_bit_cast(unsigned short, h);
}

// RNE pack (used in casts / GEMM epilogues, off the hot path)
static __device__ __forceinline__ unsigned int pack2(float lo, float hi) {
  return (unsigned int)bfbits(lo) | ((unsigned int)bfbits(hi) << 16);
}

// truncation pack: ~1 VALU inst (v_perm). P in [0,1]; bias cancels because
// lsum is computed from the SAME truncated fragments (consistent weights).
static __device__ __forceinline__ unsigned int pack2t(float lo, float hi) {
  return (__builtin_bit_cast(unsigned int, lo) >> 16) |
         (__builtin_bit_cast(unsigned int, hi) & 0xffff0000u);
}

// ---------------------------------------------------------------- fused cast kernel
// cast_w + cast_x merged into ONE launch (saves a dispatch + launch gap on the
// serialized stream). z 0-3: weights (1 rep, 512 blocks covers 1M floats/8);
// z 4-6: activations (8 reps, stride 512 blocks covers 8M floats/8).
// Routing is per-block uniform; math identical to the old kernels.
__global__ __launch_bounds__(256) void cast_all(const float* __restrict__ q,
                                                const float* __restrict__ k,
                                                const float* __restrict__ v,
                                                const float* __restrict__ wq,
                                                const float* __restrict__ wk,
                                                const float* __restrict__ wv,
                                                const float* __restrict__ wo,
                                                bf16* Xq, bf16* Xk, bf16* Xv,
                                                bf16* Wq, bf16* Wk, bf16* Wv, bf16* Wo,
                                                float s1) {
  const int z = blockIdx.z;
  const float* in;
  bf16* out;
  float s = 1.0f;
  int reps;
  if (z < 4) {
    in  = z == 0 ? wq : (z == 1 ? wk : (z == 2 ? wv : wo));
    out = z == 0 ? Wq : (z == 1 ? Wk : (z == 2 ? Wv : Wo));
    if (z == 1) s = s1;
    reps = 1;
  } else {
    in  = z == 4 ? q : (z == 5 ? k : v);
    out = z == 4 ? Xq : (z == 5 ? Xk : Xv);
    reps = 8;
  }
  const float4* p = (const float4*)in;
  for (int j = 0; j < reps; ++j) {
    size_t i = (size_t)(blockIdx.x + j * 512) * 256 + threadIdx.x;
    float4 a = p[2 * i];
    float4 b = p[2 * i + 1];
    uint4t u;
    u.x = pack2(a.x * s, a.y * s);
    u.y = pack2(a.z * s, a.w * s);
    u.z = pack2(b.x * s, b.y * s);
    u.w = pack2(b.z * s, b.w * s);
    *(uint4t*)(out + i * 8) = u;
  }
}

// ------------------------------------------------------------ shared GEMM loop pieces
// Double-buffered 2-phase (T3-minimum recipe): STAGE(next, other buf) issued
// BEFORE ds_read+MFMA of current buf; single vmcnt(0)+barrier per tile.
// (R6's 3-buf counted-vmcnt pipeline FAILED correctness — this is the
// race-screened R3 structure. Do not change sync structure.)
#define GEMM_STAGE(BUFOFF, KT) do {                                   \
    load_lds16(Ag0 + (KT), As + (BUFOFF) + w * 512);                  \
    load_lds16(Ag1 + (KT), As + (BUFOFF) + 2048 + w * 512);           \
    load_lds16(Bg0 + (KT), Bs + (BUFOFF) + w * 512);                  \
    load_lds16(Bg1 + (KT), Bs + (BUFOFF) + 2048 + w * 512);           \
  } while (0)

#define GEMM_COMPUTE(BUFOFF) do {                                              \
    short8 af[4], bf_[4];                                                      \
    _Pragma("unroll") for (int i = 0; i < 4; ++i) {                            \
      af[i]  = *(const short8*)(As + (BUFOFF) + (wm + i * 16 + lm) * 32 + lq * 8); \
      bf_[i] = *(const short8*)(Bs + (BUFOFF) + (wn + i * 16 + lm) * 32 + lq * 8); \
    }                                                                          \
    _Pragma("unroll") for (int i = 0; i < 4; ++i)                              \
      _Pragma("unroll") for (int j = 0; j < 4; ++j)                            \
        acc[i][j] = MFMA32(af[i], bf_[j], acc[i][j]);                          \
  } while (0)

#define VMCNT0_BAR() do {                                   \
    asm volatile("s_waitcnt vmcnt(0)" ::: "memory");        \
    __syncthreads();                                        \
  } while (0)

// ---------------------------------------------------------------- projection GEMMs
// Grid is (M-tiles, N-tiles, z): linear id = mTile + 64*nTile, so id%8 (XCD)
// = mTile%8 -> each XCD keeps an ~2MB A row-chunk L2-resident across all 8
// N-tiles. FETCH_SIZE 57.4MB ~= ideal (R8 counters).
__global__ __launch_bounds__(256) void gemm_proj(const bf16* __restrict__ A0,
                                                 const bf16* __restrict__ A1,
                                                 const bf16* __restrict__ A2,
                                                 const bf16* __restrict__ B0,
                                                 const bf16* __restrict__ B1,
                                                 const bf16* __restrict__ B2,
                                                 bf16* C0, bf16* C1, bf16* C2) {
  const int z = blockIdx.z;
  const bf16* A = z == 0 ? A0 : (z == 1 ? A1 : A2);
  const bf16* B = z == 0 ? B0 : (z == 1 ? B1 : B2);
  bf16* C = z == 0 ? C0 : (z == 1 ? C1 : C2);
  const int M = MROWS, N = D_MODEL, K = D_MODEL;

  __shared__ bf16 As[2 * 128 * 32];
  __shared__ bf16 Bs[2 * 128 * 32];
  const int t = threadIdx.x;
  const int w = t >> 6;
  const int lane = t & 63;
  const int lm = lane & 15;
  const int lq = lane >> 4;
  const int wm = (w >> 1) * 64;
  const int wn = (w & 1) * 64;
  const long rowA = (long)blockIdx.x * 128;   // M-tile (grid transposed)
  const long rowB = (long)blockIdx.y * 128;   // N-tile

  const int srow = t >> 2;
  const int scol = (t & 3) * 8;
  const bf16* Ag0 = A + (rowA + srow) * K + scol;
  const bf16* Ag1 = A + (rowA + 64 + srow) * K + scol;
  const bf16* Bg0 = B + (rowB + srow) * K + scol;
  const bf16* Bg1 = B + (rowB + 64 + srow) * K + scol;

  const f32x4 fzero = {0.f, 0.f, 0.f, 0.f};
  f32x4 acc[4][4];
#pragma unroll
  for (int i = 0; i < 4; ++i)
#pragma unroll
    for (int j = 0; j < 4; ++j) acc[i][j] = fzero;

  GEMM_STAGE(0, 0);
  VMCNT0_BAR();
  for (int kt = 0; kt < K; kt += 64) {
    if (kt + 32 < K) GEMM_STAGE(4096, kt + 32);
    GEMM_COMPUTE(0);
    VMCNT0_BAR();
    if (kt + 64 < K) GEMM_STAGE(0, kt + 64);
    GEMM_COMPUTE(4096);
    VMCNT0_BAR();
  }

  if (z < 2) {
#pragma unroll
    for (int i = 0; i < 4; ++i) {
      long r0 = rowA + wm + i * 16 + lq * 4;
#pragma unroll
      for (int j = 0; j < 4; ++j) {
        long c = rowB + wn + j * 16 + lm;
#pragma unroll
        for (int r = 0; r < 4; ++r)
          C[(r0 + r) * N + c] = __float2bfloat16(acc[i][j][r]);
      }
    }
  } else {
    // Vt[d][s'] with s' kv-interleaved: s=tile*64+half*16+m -> s'=tile*64+m*2+half
#pragma unroll
    for (int j = 0; j < 4; ++j) {
      long c = rowB + wn + j * 16 + lm;  // d
#pragma unroll
      for (int i = 0; i < 4; ++i) {
        long r0 = rowA + wm + i * 16 + lq * 4;  // s base, 4 consecutive
        long sp = (r0 & ~63L) | (((r0 >> 5) & 1) * 32) | ((r0 & 15) * 2) | ((r0 >> 4) & 1);
#pragma unroll
        for (int r = 0; r < 4; ++r)
          C[c * M + sp + r * 2] = __float2bfloat16(acc[i][j][r]);
      }
    }
  }
}

// ---------------------------------------------------------------- output GEMM (+bias, fp32 out)
__global__ __launch_bounds__(256) void gemm_out(const bf16* __restrict__ A,
                                                const bf16* __restrict__ B,
                                                float* __restrict__ C,
                                                const float* __restrict__ bias) {
  const int M = MROWS, N = D_MODEL, K = D_MODEL;
  __shared__ bf16 As[2 * 128 * 32];
  __shared__ bf16 Bs[2 * 128 * 32];
  const int t = threadIdx.x;
  const int w = t >> 6;
  const int lane = t & 63;
  const int lm = lane & 15;
  const int lq = lane >> 4;
  const int wm = (w >> 1) * 64;
  const int wn = (w & 1) * 64;
  const long rowA = (long)blockIdx.x * 128;   // M-tile (grid transposed)
  const long rowB = (long)blockIdx.y * 128;   // N-tile

  const int srow = t >> 2;
  const int scol = (t & 3) * 8;
  const bf16* Ag0 = A + (rowA + srow) * K + scol;
  const bf16* Ag1 = A + (rowA + 64 + srow) * K + scol;
  const bf16* Bg0 = B + (rowB + srow) * K + scol;
  const bf16* Bg1 = B + (rowB + 64 + srow) * K + scol;

  const f32x4 fzero = {0.f, 0.f, 0.f, 0.f};
  f32x4 acc[4][4];
#pragma unroll
  for (int i = 0; i < 4; ++i)
#pragma unroll
    for (int j = 0; j < 4; ++j) acc[i][j] = fzero;

  GEMM_STAGE(0, 0);
  VMCNT0_BAR();
  for (int kt = 0; kt < K; kt += 64) {
    if (kt + 32 < K) GEMM_STAGE(4096, kt + 32);
    GEMM_COMPUTE(0);
    VMCNT0_BAR();
    if (kt + 64 < K) GEMM_STAGE(0, kt + 64);
    GEMM_COMPUTE(4096);
    VMCNT0_BAR();
  }

#pragma unroll
  for (int j = 0; j < 4; ++j) {
    long c = rowB + wn + j * 16 + lm;
    float bz = bias[c];
#pragma unroll
    for (int i = 0; i < 4; ++i) {
      long r0 = rowA + wm + i * 16 + lq * 4;
#pragma unroll
      for (int r = 0; r < 4; ++r)
        C[(r0 + r) * N + c] = acc[i][j][r] + bz;
    }
  }
}

// ---------------------------------------------------------------- flash attention v5 (R3-exact, verified 73.6-74.0 µs)
__global__ __launch_bounds__(256, 4) void attn_kernel(const bf16* __restrict__ Qb,
                                                      const bf16* __restrict__ Kb,
                                                      const bf16* __restrict__ Vt,
                                                      bf16* __restrict__ ctx) {
  __shared__ bf16 Ks[64 * 64];
  __shared__ bf16 Vs[64 * 64];
  const int t = threadIdx.x;
  const int w = t >> 6;
  const int lane = t & 63;
  const int lm = lane & 15;
  const int lq = lane >> 4;
  const int bh = blockIdx.x;
  const int b = bh >> 4;
  const int h = bh & 15;
  const int q0 = blockIdx.y * 128 + w * 32;

  const bf16* Qh = Qb + (long)b * SEQ * D_MODEL + h * DK;
  const bf16* Kh = Kb + (long)b * SEQ * D_MODEL + h * DK;
  const bf16* Vh = Vt + (long)h * DK * MROWS + (long)b * SEQ;

  const int sr = lane >> 3;
  const int sc = ((lane & 7) ^ sr) * 8;      // XOR-swizzled staging column
  const bf16* kg0 = Kh + (long)(w * 8 + sr) * D_MODEL + sc;
  const bf16* kg1 = Kh + (long)(32 + w * 8 + sr) * D_MODEL + sc;
  const bf16* vg0 = Vh + (long)(w * 8 + sr) * MROWS + sc;
  const bf16* vg1 = Vh + (long)(32 + w * 8 + sr) * MROWS + sc;
  bf16* lk0 = Ks + w * 512;
  bf16* lk1 = Ks + 2048 + w * 512;
  bf16* lv0 = Vs + w * 512;
  bf16* lv1 = Vs + 2048 + w * 512;

  short8 qf[2][2];
#pragma unroll
  for (int qt = 0; qt < 2; ++qt)
#pragma unroll
    for (int ks = 0; ks < 2; ++ks)
      qf[qt][ks] = *(const short8*)(Qh + (long)(q0 + qt * 16 + lm) * D_MODEL + ks * 32 + lq * 8);

  uint4t uo;
  uo.x = 0x3F803F80u; uo.y = 0x3F803F80u; uo.z = 0x3F803F80u; uo.w = 0x3F803F80u;
  const short8 ones8 = __builtin_bit_cast(short8, uo);

  const f32x4 fzero = {0.f, 0.f, 0.f, 0.f};
  f32x4 O[2][4];
  f32x4 lsum[2];
#pragma unroll
  for (int qt = 0; qt < 2; ++qt) {
    lsum[qt] = fzero;
#pragma unroll
    for (int dt = 0; dt < 4; ++dt) O[qt][dt] = fzero;
  }

  const int xs = lm & 7;

  for (int kv = 0; kv < SEQ; kv += 64) {
    load_lds16(kg0, lk0);
    load_lds16(kg1, lk1);
    load_lds16(vg0, lv0);
    load_lds16(vg1, lv1);
    kg0 += 64 * D_MODEL; kg1 += 64 * D_MODEL;
    vg0 += 64; vg1 += 64;
    asm volatile("s_waitcnt vmcnt(0)" ::: "memory");
    __syncthreads();

    short8 kf[4][2];
#pragma unroll
    for (int c = 0; c < 4; ++c)
#pragma unroll
      for (int ks = 0; ks < 2; ++ks)
        kf[c][ks] = *(const short8*)(Ks + (c * 16 + lm) * 64 + (((ks * 4 + lq) ^ xs) * 8));
    short8 vf[4][2];
#pragma unroll
    for (int dt = 0; dt < 4; ++dt)
#pragma unroll
      for (int tt = 0; tt < 2; ++tt)
        vf[dt][tt] = *(const short8*)(Vs + (dt * 16 + lm) * 64 + (((tt * 4 + lq) ^ xs) * 8));

#pragma unroll
    for (int qt = 0; qt < 2; ++qt) {
      f32x4 st[4];
      // first K-slice consumes the persistent zero C (no per-qt re-zeroing)
#pragma unroll
      for (int c = 0; c < 4; ++c)
        st[c] = MFMA32(kf[c][0], qf[qt][0], fzero);
#pragma unroll
      for (int c = 0; c < 4; ++c)
        st[c] = MFMA32(kf[c][1], qf[qt][1], st[c]);  // St[kv][q], pre-scaled

      float pe[4][4];
#pragma unroll
      for (int c = 0; c < 4; ++c)
#pragma unroll
        for (int r = 0; r < 4; ++r)
          pe[c][r] = __builtin_amdgcn_exp2f(st[c][r]);

      short8 pf8[2];
#pragma unroll
      for (int tt = 0; tt < 2; ++tt) {
        uint4t u;
        u.x = pack2t(pe[2 * tt][0], pe[2 * tt + 1][0]);
        u.y = pack2t(pe[2 * tt][1], pe[2 * tt + 1][1]);
        u.z = pack2t(pe[2 * tt][2], pe[2 * tt + 1][2]);
        u.w = pack2t(pe[2 * tt][3], pe[2 * tt + 1][3]);
        pf8[tt] = __builtin_bit_cast(short8, u);
      }

#pragma unroll
      for (int tt = 0; tt < 2; ++tt) {
        lsum[qt] = MFMA32(pf8[tt], ones8, lsum[qt]);
#pragma unroll
        for (int dt = 0; dt < 4; ++dt)
          O[qt][dt] = MFMA32(pf8[tt], vf[dt][tt], O[qt][dt]);
      }
    }
    __syncthreads();
  }

#pragma unroll
  for (int qt = 0; qt < 2; ++qt) {
    f32x4 linv;
#pragma unroll
    for (int r = 0; r < 4; ++r) linv[r] = 1.f / lsum[qt][r];
#pragma unroll
    for (int r = 0; r < 4; ++r) {
      long qrow = (long)b * SEQ + q0 + qt * 16 + lq * 4 + r;
#pragma unroll
      for (int dt = 0; dt < 4; ++dt)
        ctx[qrow * D_MODEL + h * DK + dt * 16 + lm] =
            __float2bfloat16(O[qt][dt][r] * linv[r]);
    }
  }
}

// ---------------------------------------------------------------- launch
extern "C" void kernel_launch(void* const* d_in, const int* in_sizes, int n_in,
                              void* d_out, int out_size, void* d_ws, size_t ws_size,
                              hipStream_t stream) {
  const float* q  = (const float*)d_in[0];
  const float* k  = (const float*)d_in[1];
  const float* v  = (const float*)d_in[2];
  const float* wq = (const float*)d_in[3];
  const float* wk = (const float*)d_in[4];
  const float* wv = (const float*)d_in[5];
  const float* wo = (const float*)d_in[6];
  const float* bo = (const float*)d_in[7];

  char* ws = (char*)d_ws;
  const size_t SZW = (size_t)D_MODEL * D_MODEL * sizeof(bf16);  // 2 MB
  const size_t SZX = (size_t)MROWS * D_MODEL * sizeof(bf16);    // 16.78 MB
  bf16* Wq = (bf16*)(ws + 0 * SZW);
  bf16* Wk = (bf16*)(ws + 1 * SZW);
  bf16* Wv = (bf16*)(ws + 2 * SZW);
  bf16* Wo = (bf16*)(ws + 3 * SZW);
  bf16* Xq = (bf16*)(ws + 4 * SZW + 0 * SZX);
  bf16* Xk = (bf16*)(ws + 4 * SZW + 1 * SZX);
  bf16* Xv = (bf16*)(ws + 4 * SZW + 2 * SZX);
  bf16* Qb = (bf16*)(ws + 4 * SZW + 3 * SZX);
  bf16* Kb = (bf16*)(ws + 4 * SZW + 4 * SZX);
  bf16* Vt = Xq;  // Xq dead after Q projection
  bf16* Cx = Xk;  // Xk dead after K projection

  const float SCL = 0.18033688011112042f;  // (1/sqrt(64)) * log2(e), folded into Wk

  // single fused cast launch: z 0-3 weights, z 4-6 activations (8 reps each)
  cast_all<<<dim3(512, 1, 7), 256, 0, stream>>>(
      q, k, v, wq, wk, wv, wo, Xq, Xk, Xv, Wq, Wk, Wv, Wo, SCL);

  // grid transposed: (M-tiles, N-tiles, z) for XCD L2 reuse of A row-panels
  gemm_proj<<<dim3(MROWS / 128, D_MODEL / 128, 3), 256, 0, stream>>>(
      Xq, Xk, Xv, Wq, Wk, Wv, Qb, Kb, Vt);

  attn_kernel<<<dim3(BATCH * NHEAD, SEQ / 128), 256, 0, stream>>>(Qb, Kb, Vt, Cx);

  gemm_out<<<dim3(MROWS / 128, D_MODEL / 128), 256, 0, stream>>>(Cx, Wo, (float*)d_out, bo);
}